// Round 13
// baseline (172.584 us; speedup 1.0000x reference)
//
#include <hip/hip_runtime.h>
#include <math.h>

#define BSZ 2
#define LSEQ 4096
#define DM 256      // d_model
#define DI 256      // d_inner
#define DS 16       // d_state
#define DR 16       // dt_rank
#define NIN 512     // 2*DI
#define NCHUNK 256
#define LCHUNK 16
#define NB2 320     // padded Bcat width (288 real: 256 dt + 32 bc)

typedef __attribute__((ext_vector_type(8))) short short8;
typedef __attribute__((ext_vector_type(4))) float floatx4;

__device__ __forceinline__ float sigmoid_f(float v) {
    return __builtin_amdgcn_rcpf(1.0f + __expf(-v));
}

__device__ __forceinline__ float exp2_f(float v) {
    return __builtin_amdgcn_exp2f(v);
}

__device__ __forceinline__ unsigned int bf16_rne(float v) {
    unsigned int u = __float_as_uint(v);
    return (u + 0x7FFFu + ((u >> 16) & 1u)) >> 16;
}

#define LOG2E 1.44269504088896340736f

// ---------------- setup: split W_in/W_out transposed + build BcatT ----------------
__global__ __launch_bounds__(512) void setup_k(const float* __restrict__ W_in,
                                               const float* __restrict__ W_out,
                                               const float* __restrict__ W_x,
                                               const float* __restrict__ W_dt,
                                               unsigned short* __restrict__ WinT_hi,
                                               unsigned short* __restrict__ WinT_lo,
                                               unsigned short* __restrict__ WoutT_hi,
                                               unsigned short* __restrict__ WoutT_lo,
                                               unsigned short* __restrict__ BcatT_hi,
                                               unsigned short* __restrict__ BcatT_lo) {
    __shared__ float wr[16];
    const int k = blockIdx.x;          // 0..255
    const int t = threadIdx.x;         // 0..511
    if (t < 16) wr[t] = W_x[(size_t)k * 48 + t];
    {
        float v = W_in[(size_t)k * NIN + t];
        unsigned int h = bf16_rne(v);
        float r = v - __uint_as_float(h << 16);
        WinT_hi[(size_t)t * DM + k] = (unsigned short)h;
        WinT_lo[(size_t)t * DM + k] = (unsigned short)bf16_rne(r);
    }
    if (t < DM) {
        float v = W_out[(size_t)k * DM + t];
        unsigned int h = bf16_rne(v);
        float r = v - __uint_as_float(h << 16);
        WoutT_hi[(size_t)t * DM + k] = (unsigned short)h;
        WoutT_lo[(size_t)t * DM + k] = (unsigned short)bf16_rne(r);
    }
    __syncthreads();
    if (t < NB2) {
        float v;
        if (t < 256) {
            float acc = 0.f;
#pragma unroll
            for (int r = 0; r < 16; ++r) acc = fmaf(wr[r], W_dt[r * DI + t], acc);
            v = acc;
        } else if (t < 288) {
            v = W_x[(size_t)k * 48 + 16 + (t - 256)];
        } else {
            v = 0.f;
        }
        unsigned int h = bf16_rne(v);
        float r = v - __uint_as_float(h << 16);
        BcatT_hi[(size_t)t * DM + k] = (unsigned short)h;
        BcatT_lo[(size_t)t * DM + k] = (unsigned short)bf16_rne(r);
    }
}

// ---------------- gemm_in (MFMA bf16x3): xz = x^T @ W_in; z-half gets SiLU in epilogue ----------------
__global__ __launch_bounds__(256) void gemm_in_k(const float* __restrict__ x,
                                                 const unsigned short* __restrict__ WT_hi,
                                                 const unsigned short* __restrict__ WT_lo,
                                                 float* __restrict__ xz) {
    __shared__ unsigned short sA[128][40];
    __shared__ unsigned short sB[128][40];
    const int b  = blockIdx.z;
    const int m0 = blockIdx.y * 64;
    const int n0 = blockIdx.x * 64;
    const int t  = threadIdx.x;
    const int w    = t >> 6;
    const int lane = t & 63;
    const int kp = t & 15;
    const int g  = t >> 4;

    const int mwb = (w & 1) * 32;
    const int nwb = (w >> 1) * 32;
    const int fr  = lane & 15;
    const int q   = lane >> 4;

    const int brow = t >> 2;
    const int bkq8 = (t & 3) * 8;

    floatx4 acc[2][2];
#pragma unroll
    for (int mi = 0; mi < 2; ++mi)
#pragma unroll
        for (int ni = 0; ni < 2; ++ni) acc[mi][ni] = (floatx4){0.f, 0.f, 0.f, 0.f};

    for (int k0 = 0; k0 < DM; k0 += 32) {
        {
            const float* pa = x + ((size_t)b * DM + k0 + 2 * kp) * LSEQ + m0 + 4 * g;
            float4 fa0 = *(const float4*)(pa);
            float4 fa1 = *(const float4*)(pa + LSEQ);
            const float* a0 = (const float*)&fa0;
            const float* a1 = (const float*)&fa1;
#pragma unroll
            for (int j = 0; j < 4; ++j) {
                int m = 4 * g + j;
                unsigned int h0 = bf16_rne(a0[j]);
                unsigned int h1 = bf16_rne(a1[j]);
                float r0 = a0[j] - __uint_as_float(h0 << 16);
                float r1 = a1[j] - __uint_as_float(h1 << 16);
                unsigned int l0 = bf16_rne(r0);
                unsigned int l1 = bf16_rne(r1);
                *(unsigned int*)&sA[m][2 * kp]      = h0 | (h1 << 16);
                *(unsigned int*)&sA[64 + m][2 * kp] = l0 | (l1 << 16);
            }
            const size_t boff = (size_t)(n0 + brow) * DM + k0 + bkq8;
            *(short8*)&sB[brow][bkq8]      = *(const short8*)(WT_hi + boff);
            *(short8*)&sB[64 + brow][bkq8] = *(const short8*)(WT_lo + boff);
        }
        __syncthreads();

        short8 ah[2], al[2], bh[2], bl[2];
#pragma unroll
        for (int mi = 0; mi < 2; ++mi) {
            int mr = mwb + mi * 16 + fr;
            ah[mi] = *(const short8*)&sA[mr][q * 8];
            al[mi] = *(const short8*)&sA[64 + mr][q * 8];
        }
#pragma unroll
        for (int ni = 0; ni < 2; ++ni) {
            int nr = nwb + ni * 16 + fr;
            bh[ni] = *(const short8*)&sB[nr][q * 8];
            bl[ni] = *(const short8*)&sB[64 + nr][q * 8];
        }
#pragma unroll
        for (int mi = 0; mi < 2; ++mi)
#pragma unroll
            for (int ni = 0; ni < 2; ++ni) {
                acc[mi][ni] = __builtin_amdgcn_mfma_f32_16x16x32_bf16(ah[mi], bh[ni], acc[mi][ni], 0, 0, 0);
                acc[mi][ni] = __builtin_amdgcn_mfma_f32_16x16x32_bf16(ah[mi], bl[ni], acc[mi][ni], 0, 0, 0);
                acc[mi][ni] = __builtin_amdgcn_mfma_f32_16x16x32_bf16(al[mi], bh[ni], acc[mi][ni], 0, 0, 0);
            }
        __syncthreads();
    }

    const bool isz = (n0 >= 256);   // z-half: store silu(z)
#pragma unroll
    for (int mi = 0; mi < 2; ++mi)
#pragma unroll
        for (int ni = 0; ni < 2; ++ni) {
#pragma unroll
            for (int r = 0; r < 4; ++r) {
                int m = m0 + mwb + mi * 16 + q * 4 + r;
                int n = n0 + nwb + ni * 16 + fr;
                float v = acc[mi][ni][r];
                if (isz) v = v * sigmoid_f(v);
                xz[((size_t)b * LSEQ + m) * NIN + n] = v;
            }
        }
}

// ---------------- gemm_x2c (MFMA bf16x3, conv+SiLU as coalesced LDS producer phase) ----------------
// [dt | bc] = silu(conv(xz_x)) @ Bcat ; n-block 0 also writes xc (fp32) for the scans.
__global__ __launch_bounds__(256) void gemm_x2c_k(const float* __restrict__ xz,
                                                  const float* __restrict__ conv_w,
                                                  const float* __restrict__ conv_b,
                                                  const unsigned short* __restrict__ BT_hi,
                                                  const unsigned short* __restrict__ BT_lo,
                                                  const float* __restrict__ b_dt,
                                                  float* __restrict__ xc,
                                                  float* __restrict__ dt,
                                                  float* __restrict__ bc) {
    __shared__ unsigned short sA[128][40];
    __shared__ unsigned short sB[128][40];
    __shared__ float sX[67][36];      // 64 rows + 3 halo; stride 36 -> 16B-aligned, 2-way-only conflicts
    __shared__ float cwL[256][4];
    __shared__ float cbL[256];
    const int m0 = blockIdx.y * 64;
    const int n0 = blockIdx.x * 64;
    const int t  = threadIdx.x;
    const int w    = t >> 6;
    const int lane = t & 63;
    const int mwb = (w & 1) * 32;
    const int nwb = (w >> 1) * 32;
    const int fr  = lane & 15;
    const int q   = lane >> 4;

    const int row = t >> 2;           // 0..63
    const int kq8 = (t & 3) * 8;      // 0,8,16,24
    const bool write_xc = (blockIdx.x == 0);
    const bool lhead = ((m0 & (LSEQ - 1)) == 0);   // block at sequence start (zero halo)

    // stage conv weights/bias once (first k-step's __syncthreads covers visibility)
    *(float4*)&cwL[t][0] = *(const float4*)(conv_w + t * 4);
    cbL[t] = conv_b[t];

    floatx4 acc[2][2];
#pragma unroll
    for (int mi = 0; mi < 2; ++mi)
#pragma unroll
        for (int ni = 0; ni < 2; ++ni) acc[mi][ni] = (floatx4){0.f, 0.f, 0.f, 0.f};

    for (int k0 = 0; k0 < DI; k0 += 32) {
        // ---- producer: stage raw xz tile (67 rows x 32 d), coalesced ----
#pragma unroll
        for (int p = 0; p < 3; ++p) {
            int slot = t + p * 256;
            if (slot < 536) {                       // 67 rows * 8 float4
                int r  = slot >> 3;
                int c4 = (slot & 7) * 4;
                float4 v4 = make_float4(0.f, 0.f, 0.f, 0.f);
                if (!(lhead && r < 3))
                    v4 = *(const float4*)(xz + (size_t)(m0 - 3 + r) * NIN + k0 + c4);
                *(float4*)&sX[r][c4] = v4;
            }
        }
        __syncthreads();

        {
            // conv + silu from LDS
            float xvv[4][8];
#pragma unroll
            for (int k = 0; k < 4; ++k) {
                *(float4*)&xvv[k][0] = *(float4*)&sX[row + k][kq8];
                *(float4*)&xvv[k][4] = *(float4*)&sX[row + k][kq8 + 4];
            }
            float v[8];
            *(float4*)(v)     = *(float4*)&cbL[k0 + kq8];
            *(float4*)(v + 4) = *(float4*)&cbL[k0 + kq8 + 4];
#pragma unroll
            for (int j = 0; j < 8; ++j) {
                float4 cwj = *(float4*)&cwL[k0 + kq8 + j][0];
                const float* cwp = (const float*)&cwj;
#pragma unroll
                for (int k = 0; k < 4; ++k)
                    v[j] = fmaf(xvv[k][j], cwp[k], v[j]);
                v[j] = v[j] * sigmoid_f(v[j]);
            }
            // split to bf16 hi/lo -> sA
            short8 hi, lo;
#pragma unroll
            for (int j = 0; j < 8; ++j) {
                unsigned int h = bf16_rne(v[j]);
                float r = v[j] - __uint_as_float(h << 16);
                hi[j] = (short)h;
                lo[j] = (short)bf16_rne(r);
            }
            *(short8*)&sA[row][kq8]      = hi;
            *(short8*)&sA[64 + row][kq8] = lo;
            if (write_xc) {
                float* pxc = xc + (size_t)(m0 + row) * DI + k0 + kq8;
                *(float4*)(pxc)     = *(float4*)(v);
                *(float4*)(pxc + 4) = *(float4*)(v + 4);
            }
            // B staging (pre-split transposed Bcat)
            const size_t boff = (size_t)(n0 + row) * DM + k0 + kq8;
            *(short8*)&sB[row][kq8]      = *(const short8*)(BT_hi + boff);
            *(short8*)&sB[64 + row][kq8] = *(const short8*)(BT_lo + boff);
        }
        __syncthreads();

        short8 ah[2], al[2], bh[2], bl[2];
#pragma unroll
        for (int mi = 0; mi < 2; ++mi) {
            int mr = mwb + mi * 16 + fr;
            ah[mi] = *(const short8*)&sA[mr][q * 8];
            al[mi] = *(const short8*)&sA[64 + mr][q * 8];
        }
#pragma unroll
        for (int ni = 0; ni < 2; ++ni) {
            int nr = nwb + ni * 16 + fr;
            bh[ni] = *(const short8*)&sB[nr][q * 8];
            bl[ni] = *(const short8*)&sB[64 + nr][q * 8];
        }
#pragma unroll
        for (int mi = 0; mi < 2; ++mi)
#pragma unroll
            for (int ni = 0; ni < 2; ++ni) {
                acc[mi][ni] = __builtin_amdgcn_mfma_f32_16x16x32_bf16(ah[mi], bh[ni], acc[mi][ni], 0, 0, 0);
                acc[mi][ni] = __builtin_amdgcn_mfma_f32_16x16x32_bf16(ah[mi], bl[ni], acc[mi][ni], 0, 0, 0);
                acc[mi][ni] = __builtin_amdgcn_mfma_f32_16x16x32_bf16(al[mi], bh[ni], acc[mi][ni], 0, 0, 0);
            }
        __syncthreads();
    }

#pragma unroll
    for (int mi = 0; mi < 2; ++mi)
#pragma unroll
        for (int ni = 0; ni < 2; ++ni) {
            int n = n0 + nwb + ni * 16 + fr;
            if (n < 256) {
                float bd = b_dt[n];
#pragma unroll
                for (int r = 0; r < 4; ++r) {
                    int m = m0 + mwb + mi * 16 + q * 4 + r;
                    float a2 = acc[mi][ni][r] + bd;
                    float sp = fmaxf(a2, 0.f) + __logf(1.f + __expf(-fabsf(a2)));
                    dt[(size_t)m * DI + n] = sp;
                }
            } else if (n < 288) {
#pragma unroll
                for (int r = 0; r < 4; ++r) {
                    int m = m0 + mwb + mi * 16 + q * 4 + r;
                    bc[(size_t)m * 32 + (n - 256)] = acc[mi][ni][r];
                }
            }
        }
}

// ---------------- scan phase A: local final F + per-chunk dt-sum ----------------
__global__ __launch_bounds__(256) void scan_a_k(const float* __restrict__ dt,
                                                const float* __restrict__ xc,
                                                const float* __restrict__ bc,
                                                const float* __restrict__ A_log,
                                                float* __restrict__ sumdt,
                                                float* __restrict__ Fst) {
    __shared__ float Bl[LCHUNK][16];
    const int blk   = blockIdx.x;
    const int b     = blk / NCHUNK;
    const int chunk = blk % NCHUNK;
    const int d     = threadIdx.x;
    const int l0    = chunk * LCHUNK;

    if (d < LCHUNK * 4) {
        int l = d >> 2, q = d & 3;
        *(float4*)(&Bl[l][q * 4]) =
            *(const float4*)(bc + (size_t)(b * LSEQ + l0 + l) * 32 + q * 4);
    }
    float Ads2[16];
#pragma unroll
    for (int s = 0; s < 16; ++s) Ads2[s] = -expf(A_log[d * DS + s]) * LOG2E;
    __syncthreads();

    float h[16];
#pragma unroll
    for (int s = 0; s < 16; ++s) h[s] = 0.f;
    float sd = 0.f;

    const float* dtp = dt + ((size_t)b * LSEQ + l0) * DI + d;
    const float* xcp = xc + ((size_t)b * LSEQ + l0) * DI + d;

#pragma unroll 4
    for (int i = 0; i < LCHUNK; ++i) {
        float dtv = dtp[(size_t)i * DI];
        float xcv = xcp[(size_t)i * DI];
        float du  = dtv * xcv;
        sd += dtv;
        float4 b0 = *(float4*)(&Bl[i][0]);
        float4 b1 = *(float4*)(&Bl[i][4]);
        float4 b2 = *(float4*)(&Bl[i][8]);
        float4 b3 = *(float4*)(&Bl[i][12]);
        float bv[16] = {b0.x,b0.y,b0.z,b0.w, b1.x,b1.y,b1.z,b1.w,
                        b2.x,b2.y,b2.z,b2.w, b3.x,b3.y,b3.z,b3.w};
#pragma unroll
        for (int s = 0; s < 16; ++s) {
            float a = exp2_f(dtv * Ads2[s]);
            h[s] = fmaf(h[s], a, du * bv[s]);
        }
    }
    size_t base = ((size_t)(b * DI + d) * NCHUNK + chunk) * DS;
#pragma unroll
    for (int q = 0; q < 4; ++q)
        *(float4*)(Fst + base + q * 4) = make_float4(h[q*4], h[q*4+1], h[q*4+2], h[q*4+3]);
    sumdt[(size_t)(b * DI + d) * NCHUNK + chunk] = sd;
}

// ---------------- scan phase B: chunk-prefix; P reconstructed from sumdt ----------------
__global__ __launch_bounds__(256) void scan_b_k(const float* __restrict__ sumdt,
                                                const float* __restrict__ A_log,
                                                float* __restrict__ Fst) {
    const int t = blockIdx.x * 256 + threadIdx.x;
    const int s = t & 15;
    const int d = (t >> 4) & (DI - 1);
    const int b = t >> 12;
    const float Ads2 = -expf(A_log[d * DS + s]) * LOG2E;
    size_t base = ((size_t)(b * DI + d) * NCHUNK) * DS + s;
    const float* sdp = sumdt + (size_t)(b * DI + d) * NCHUNK;
    float st = 0.f;
#pragma unroll 8
    for (int c = 0; c < NCHUNK; ++c) {
        size_t idx = base + (size_t)c * DS;
        float P = exp2_f(sdp[c] * Ads2);
        float F = Fst[idx];
        Fst[idx] = st;
        st = fmaf(P, st, F);
    }
}

// ---------------- scan phase C ----------------
__global__ __launch_bounds__(256) void scan_c_k(const float* __restrict__ dt,
                                                const float* __restrict__ xc,
                                                const float* __restrict__ bc,
                                                const float* __restrict__ xz,
                                                const float* __restrict__ A_log,
                                                const float* __restrict__ Dw,
                                                const float* __restrict__ carry,
                                                float* __restrict__ y) {
    __shared__ float BC[LCHUNK][32];
    const int blk   = blockIdx.x;
    const int b     = blk / NCHUNK;
    const int chunk = blk % NCHUNK;
    const int d     = threadIdx.x;
    const int l0    = chunk * LCHUNK;

    if (d < LCHUNK * 8) {
        int l = d >> 3, q = d & 7;
        *(float4*)(&BC[l][q * 4]) =
            *(const float4*)(bc + (size_t)(b * LSEQ + l0 + l) * 32 + q * 4);
    }
    float Ads2[16];
#pragma unroll
    for (int s = 0; s < 16; ++s) Ads2[s] = -expf(A_log[d * DS + s]) * LOG2E;
    const float Dd = Dw[d];

    float h[16];
    size_t cbase = ((size_t)(b * DI + d) * NCHUNK + chunk) * DS;
#pragma unroll
    for (int q = 0; q < 4; ++q) {
        float4 c4 = *(const float4*)(carry + cbase + q * 4);
        h[q*4] = c4.x; h[q*4+1] = c4.y; h[q*4+2] = c4.z; h[q*4+3] = c4.w;
    }
    __syncthreads();

    const float* dtp = dt + ((size_t)b * LSEQ + l0) * DI + d;
    const float* xcp = xc + ((size_t)b * LSEQ + l0) * DI + d;
    const float* zp  = xz + ((size_t)b * LSEQ + l0) * NIN + DI + d;   // already silu'd
    float* yout      = y  + ((size_t)b * LSEQ + l0) * DI + d;

#pragma unroll 4
    for (int i = 0; i < LCHUNK; ++i) {
        float dtv = dtp[(size_t)i * DI];
        float xcv = xcp[(size_t)i * DI];
        float zs  = zp[(size_t)i * NIN];
        float du  = dtv * xcv;
        float4 b0 = *(float4*)(&BC[i][0]);
        float4 b1 = *(float4*)(&BC[i][4]);
        float4 b2 = *(float4*)(&BC[i][8]);
        float4 b3 = *(float4*)(&BC[i][12]);
        float4 c0 = *(float4*)(&BC[i][16]);
        float4 c1 = *(float4*)(&BC[i][20]);
        float4 c2 = *(float4*)(&BC[i][24]);
        float4 c3 = *(float4*)(&BC[i][28]);
        float bv[16] = {b0.x,b0.y,b0.z,b0.w, b1.x,b1.y,b1.z,b1.w,
                        b2.x,b2.y,b2.z,b2.w, b3.x,b3.y,b3.z,b3.w};
        float cv[16] = {c0.x,c0.y,c0.z,c0.w, c1.x,c1.y,c1.z,c1.w,
                        c2.x,c2.y,c2.z,c2.w, c3.x,c3.y,c3.z,c3.w};
        float yv = 0.f;
#pragma unroll
        for (int s = 0; s < 16; ++s) {
            float a = exp2_f(dtv * Ads2[s]);
            h[s] = fmaf(h[s], a, du * bv[s]);
            yv = fmaf(h[s], cv[s], yv);
        }
        float yf = fmaf(xcv, Dd, yv);
        yout[(size_t)i * DI] = yf * zs;
    }
}

// ---------------- gemm_out (MFMA bf16x3): out[b,c,l] = sum_d y[b,l,d] * W_out[d,c] ----------------
__global__ __launch_bounds__(256) void gemm_out_k(const float* __restrict__ y,
                                                  const unsigned short* __restrict__ WT_hi,
                                                  const unsigned short* __restrict__ WT_lo,
                                                  float* __restrict__ out) {
    __shared__ unsigned short sA[128][40];
    __shared__ unsigned short sB[128][40];
    const int b  = blockIdx.z;
    const int m0 = blockIdx.y * 64;    // l
    const int n0 = blockIdx.x * 64;    // c
    const int t  = threadIdx.x;
    const int w    = t >> 6;
    const int lane = t & 63;
    const int mwb = (w & 1) * 32;
    const int nwb = (w >> 1) * 32;
    const int fr  = lane & 15;
    const int q   = lane >> 4;

    const int row = t >> 2;
    const int kq8 = (t & 3) * 8;

    floatx4 acc[2][2];
#pragma unroll
    for (int mi = 0; mi < 2; ++mi)
#pragma unroll
        for (int ni = 0; ni < 2; ++ni) acc[mi][ni] = (floatx4){0.f, 0.f, 0.f, 0.f};

    for (int k0 = 0; k0 < DI; k0 += 32) {
        {
            const float* pa = y + ((size_t)b * LSEQ + m0 + row) * DI + k0 + kq8;
            float v[8];
            *(float4*)(v)     = *(const float4*)(pa);
            *(float4*)(v + 4) = *(const float4*)(pa + 4);
            short8 hi, lo;
#pragma unroll
            for (int j = 0; j < 8; ++j) {
                unsigned int h = bf16_rne(v[j]);
                float r = v[j] - __uint_as_float(h << 16);
                hi[j] = (short)h;
                lo[j] = (short)bf16_rne(r);
            }
            *(short8*)&sA[row][kq8]      = hi;
            *(short8*)&sA[64 + row][kq8] = lo;

            const size_t boff = (size_t)(n0 + row) * DM + k0 + kq8;
            *(short8*)&sB[row][kq8]      = *(const short8*)(WT_hi + boff);
            *(short8*)&sB[64 + row][kq8] = *(const short8*)(WT_lo + boff);
        }
        __syncthreads();

        short8 ah[2], al[2], bh[2], bl[2];
#pragma unroll
        for (int mi = 0; mi < 2; ++mi) {
            int mr = mwb + mi * 16 + fr;
            ah[mi] = *(const short8*)&sA[mr][q * 8];
            al[mi] = *(const short8*)&sA[64 + mr][q * 8];
        }
#pragma unroll
        for (int ni = 0; ni < 2; ++ni) {
            int nr = nwb + ni * 16 + fr;
            bh[ni] = *(const short8*)&sB[nr][q * 8];
            bl[ni] = *(const short8*)&sB[64 + nr][q * 8];
        }
#pragma unroll
        for (int mi = 0; mi < 2; ++mi)
#pragma unroll
            for (int ni = 0; ni < 2; ++ni) {
                acc[mi][ni] = __builtin_amdgcn_mfma_f32_16x16x32_bf16(ah[mi], bh[ni], acc[mi][ni], 0, 0, 0);
                acc[mi][ni] = __builtin_amdgcn_mfma_f32_16x16x32_bf16(ah[mi], bl[ni], acc[mi][ni], 0, 0, 0);
                acc[mi][ni] = __builtin_amdgcn_mfma_f32_16x16x32_bf16(al[mi], bh[ni], acc[mi][ni], 0, 0, 0);
            }
        __syncthreads();
    }

#pragma unroll
    for (int mi = 0; mi < 2; ++mi)
#pragma unroll
        for (int ni = 0; ni < 2; ++ni) {
            int c = n0 + nwb + ni * 16 + fr;
            float* op = out + ((size_t)b * DM + c) * LSEQ + m0 + mwb + mi * 16 + q * 4;
            *(float4*)op = make_float4(acc[mi][ni][0], acc[mi][ni][1],
                                       acc[mi][ni][2], acc[mi][ni][3]);
        }
}

extern "C" void kernel_launch(void* const* d_in, const int* in_sizes, int n_in,
                              void* d_out, int out_size, void* d_ws, size_t ws_size,
                              hipStream_t stream) {
    const float* x      = (const float*)d_in[0];
    const float* W_in   = (const float*)d_in[1];
    const float* conv_w = (const float*)d_in[2];
    const float* conv_b = (const float*)d_in[3];
    const float* W_x    = (const float*)d_in[4];
    const float* W_dt   = (const float*)d_in[5];
    const float* b_dt   = (const float*)d_in[6];
    const float* A_log  = (const float*)d_in[7];
    const float* Dw     = (const float*)d_in[8];
    const float* W_out  = (const float*)d_in[9];
    float* out = (float*)d_out;

    float* ws    = (float*)d_ws;
    float* xz    = ws;                    // B*L*512            = 4,194,304
    float* xc    = xz + 4194304;          // B*L*256            = 2,097,152
    float* bc    = xc + 2097152;          // B*L*32             =   262,144
    float* dtb   = bc + 262144;           // B*L*256            = 2,097,152
    float* sumdt = dtb + 2097152;         // B*DI*NCHUNK        =   131,072
    float* Fst   = sumdt + 131072;        // B*DI*NCHUNK*DS     = 2,097,152
    float* yb    = Fst + 2097152;         // B*L*DI             = 2,097,152
    unsigned short* WinT_hi  = (unsigned short*)(yb + 2097152);   // 512*256
    unsigned short* WinT_lo  = WinT_hi + 131072;
    unsigned short* WoutT_hi = WinT_lo + 131072;                  // 256*256
    unsigned short* WoutT_lo = WoutT_hi + 65536;
    unsigned short* BcatT_hi = WoutT_lo + 65536;                  // 320*256
    unsigned short* BcatT_lo = BcatT_hi + 81920;

    setup_k    <<<dim3(256), 512, 0, stream>>>(W_in, W_out, W_x, W_dt,
                                               WinT_hi, WinT_lo, WoutT_hi, WoutT_lo,
                                               BcatT_hi, BcatT_lo);
    gemm_in_k  <<<dim3(8, 64, BSZ), 256, 0, stream>>>(x, WinT_hi, WinT_lo, xz);
    gemm_x2c_k <<<dim3(5, 128), 256, 0, stream>>>(xz, conv_w, conv_b,
                                                  BcatT_hi, BcatT_lo, b_dt, xc, dtb, bc);
    scan_a_k   <<<dim3(BSZ * NCHUNK), 256, 0, stream>>>(dtb, xc, bc, A_log, sumdt, Fst);
    scan_b_k   <<<dim3(BSZ * DI * DS / 256), 256, 0, stream>>>(sumdt, A_log, Fst);
    scan_c_k   <<<dim3(BSZ * NCHUNK), 256, 0, stream>>>(dtb, xc, bc, xz, A_log, Dw, Fst, yb);
    gemm_out_k <<<dim3(4, 64, BSZ), 256, 0, stream>>>(yb, WoutT_hi, WoutT_lo, out);
}

// Round 14
// 162.648 us; speedup vs baseline: 1.0611x; 1.0611x over previous
//
#include <hip/hip_runtime.h>
#include <math.h>

#define BSZ 2
#define LSEQ 4096
#define DM 256      // d_model
#define DI 256      // d_inner
#define DS 16       // d_state
#define DR 16       // dt_rank
#define NIN 512     // 2*DI
#define NCHUNK 256
#define LCHUNK 16
#define NB2 320     // padded Bcat width (288 real: 256 dt + 32 bc)

typedef __attribute__((ext_vector_type(8))) short short8;
typedef __attribute__((ext_vector_type(4))) float floatx4;

__device__ __forceinline__ float sigmoid_f(float v) {
    return __builtin_amdgcn_rcpf(1.0f + __expf(-v));
}

__device__ __forceinline__ float exp2_f(float v) {
    return __builtin_amdgcn_exp2f(v);
}

__device__ __forceinline__ unsigned int bf16_rne(float v) {
    unsigned int u = __float_as_uint(v);
    return (u + 0x7FFFu + ((u >> 16) & 1u)) >> 16;
}

#define LOG2E 1.44269504088896340736f

// ---------------- setup: split W_in/W_out transposed + build BcatT ----------------
__global__ __launch_bounds__(512) void setup_k(const float* __restrict__ W_in,
                                               const float* __restrict__ W_out,
                                               const float* __restrict__ W_x,
                                               const float* __restrict__ W_dt,
                                               unsigned short* __restrict__ WinT_hi,
                                               unsigned short* __restrict__ WinT_lo,
                                               unsigned short* __restrict__ WoutT_hi,
                                               unsigned short* __restrict__ WoutT_lo,
                                               unsigned short* __restrict__ BcatT_hi,
                                               unsigned short* __restrict__ BcatT_lo) {
    __shared__ float wr[16];
    const int k = blockIdx.x;          // 0..255
    const int t = threadIdx.x;         // 0..511
    if (t < 16) wr[t] = W_x[(size_t)k * 48 + t];
    {
        float v = W_in[(size_t)k * NIN + t];
        unsigned int h = bf16_rne(v);
        float r = v - __uint_as_float(h << 16);
        WinT_hi[(size_t)t * DM + k] = (unsigned short)h;
        WinT_lo[(size_t)t * DM + k] = (unsigned short)bf16_rne(r);
    }
    if (t < DM) {
        float v = W_out[(size_t)k * DM + t];
        unsigned int h = bf16_rne(v);
        float r = v - __uint_as_float(h << 16);
        WoutT_hi[(size_t)t * DM + k] = (unsigned short)h;
        WoutT_lo[(size_t)t * DM + k] = (unsigned short)bf16_rne(r);
    }
    __syncthreads();
    if (t < NB2) {
        float v;
        if (t < 256) {
            float acc = 0.f;
#pragma unroll
            for (int r = 0; r < 16; ++r) acc = fmaf(wr[r], W_dt[r * DI + t], acc);
            v = acc;
        } else if (t < 288) {
            v = W_x[(size_t)k * 48 + 16 + (t - 256)];
        } else {
            v = 0.f;
        }
        unsigned int h = bf16_rne(v);
        float r = v - __uint_as_float(h << 16);
        BcatT_hi[(size_t)t * DM + k] = (unsigned short)h;
        BcatT_lo[(size_t)t * DM + k] = (unsigned short)bf16_rne(r);
    }
}

// ---------------- gemm_in (MFMA bf16x3): xz = x^T @ W_in; z-half gets SiLU in epilogue ----------------
__global__ __launch_bounds__(256) void gemm_in_k(const float* __restrict__ x,
                                                 const unsigned short* __restrict__ WT_hi,
                                                 const unsigned short* __restrict__ WT_lo,
                                                 float* __restrict__ xz) {
    __shared__ unsigned short sA[128][40];
    __shared__ unsigned short sB[128][40];
    const int b  = blockIdx.z;
    const int m0 = blockIdx.y * 64;
    const int n0 = blockIdx.x * 64;
    const int t  = threadIdx.x;
    const int w    = t >> 6;
    const int lane = t & 63;
    const int kp = t & 15;
    const int g  = t >> 4;

    const int mwb = (w & 1) * 32;
    const int nwb = (w >> 1) * 32;
    const int fr  = lane & 15;
    const int q   = lane >> 4;

    const int brow = t >> 2;
    const int bkq8 = (t & 3) * 8;

    floatx4 acc[2][2];
#pragma unroll
    for (int mi = 0; mi < 2; ++mi)
#pragma unroll
        for (int ni = 0; ni < 2; ++ni) acc[mi][ni] = (floatx4){0.f, 0.f, 0.f, 0.f};

    for (int k0 = 0; k0 < DM; k0 += 32) {
        {
            const float* pa = x + ((size_t)b * DM + k0 + 2 * kp) * LSEQ + m0 + 4 * g;
            float4 fa0 = *(const float4*)(pa);
            float4 fa1 = *(const float4*)(pa + LSEQ);
            const float* a0 = (const float*)&fa0;
            const float* a1 = (const float*)&fa1;
#pragma unroll
            for (int j = 0; j < 4; ++j) {
                int m = 4 * g + j;
                unsigned int h0 = bf16_rne(a0[j]);
                unsigned int h1 = bf16_rne(a1[j]);
                float r0 = a0[j] - __uint_as_float(h0 << 16);
                float r1 = a1[j] - __uint_as_float(h1 << 16);
                unsigned int l0 = bf16_rne(r0);
                unsigned int l1 = bf16_rne(r1);
                *(unsigned int*)&sA[m][2 * kp]      = h0 | (h1 << 16);
                *(unsigned int*)&sA[64 + m][2 * kp] = l0 | (l1 << 16);
            }
            const size_t boff = (size_t)(n0 + brow) * DM + k0 + bkq8;
            *(short8*)&sB[brow][bkq8]      = *(const short8*)(WT_hi + boff);
            *(short8*)&sB[64 + brow][bkq8] = *(const short8*)(WT_lo + boff);
        }
        __syncthreads();

        short8 ah[2], al[2], bh[2], bl[2];
#pragma unroll
        for (int mi = 0; mi < 2; ++mi) {
            int mr = mwb + mi * 16 + fr;
            ah[mi] = *(const short8*)&sA[mr][q * 8];
            al[mi] = *(const short8*)&sA[64 + mr][q * 8];
        }
#pragma unroll
        for (int ni = 0; ni < 2; ++ni) {
            int nr = nwb + ni * 16 + fr;
            bh[ni] = *(const short8*)&sB[nr][q * 8];
            bl[ni] = *(const short8*)&sB[64 + nr][q * 8];
        }
#pragma unroll
        for (int mi = 0; mi < 2; ++mi)
#pragma unroll
            for (int ni = 0; ni < 2; ++ni) {
                acc[mi][ni] = __builtin_amdgcn_mfma_f32_16x16x32_bf16(ah[mi], bh[ni], acc[mi][ni], 0, 0, 0);
                acc[mi][ni] = __builtin_amdgcn_mfma_f32_16x16x32_bf16(ah[mi], bl[ni], acc[mi][ni], 0, 0, 0);
                acc[mi][ni] = __builtin_amdgcn_mfma_f32_16x16x32_bf16(al[mi], bh[ni], acc[mi][ni], 0, 0, 0);
            }
        __syncthreads();
    }

    const bool isz = (n0 >= 256);   // z-half: store silu(z)
#pragma unroll
    for (int mi = 0; mi < 2; ++mi)
#pragma unroll
        for (int ni = 0; ni < 2; ++ni) {
#pragma unroll
            for (int r = 0; r < 4; ++r) {
                int m = m0 + mwb + mi * 16 + q * 4 + r;
                int n = n0 + nwb + ni * 16 + fr;
                float v = acc[mi][ni][r];
                if (isz) v = v * sigmoid_f(v);
                xz[((size_t)b * LSEQ + m) * NIN + n] = v;
            }
        }
}

// ---------------- gemm_x2c (MFMA bf16x3, conv+SiLU as coalesced LDS producer phase) ----------------
__global__ __launch_bounds__(256) void gemm_x2c_k(const float* __restrict__ xz,
                                                  const float* __restrict__ conv_w,
                                                  const float* __restrict__ conv_b,
                                                  const unsigned short* __restrict__ BT_hi,
                                                  const unsigned short* __restrict__ BT_lo,
                                                  const float* __restrict__ b_dt,
                                                  float* __restrict__ xc,
                                                  float* __restrict__ dt,
                                                  float* __restrict__ bc) {
    __shared__ unsigned short sA[128][40];
    __shared__ unsigned short sB[128][40];
    __shared__ float sX[67][36];
    __shared__ float cwL[256][4];
    __shared__ float cbL[256];
    const int m0 = blockIdx.y * 64;
    const int n0 = blockIdx.x * 64;
    const int t  = threadIdx.x;
    const int w    = t >> 6;
    const int lane = t & 63;
    const int mwb = (w & 1) * 32;
    const int nwb = (w >> 1) * 32;
    const int fr  = lane & 15;
    const int q   = lane >> 4;

    const int row = t >> 2;           // 0..63
    const int kq8 = (t & 3) * 8;      // 0,8,16,24
    const bool write_xc = (blockIdx.x == 0);
    const bool lhead = ((m0 & (LSEQ - 1)) == 0);

    *(float4*)&cwL[t][0] = *(const float4*)(conv_w + t * 4);
    cbL[t] = conv_b[t];

    floatx4 acc[2][2];
#pragma unroll
    for (int mi = 0; mi < 2; ++mi)
#pragma unroll
        for (int ni = 0; ni < 2; ++ni) acc[mi][ni] = (floatx4){0.f, 0.f, 0.f, 0.f};

    for (int k0 = 0; k0 < DI; k0 += 32) {
#pragma unroll
        for (int p = 0; p < 3; ++p) {
            int slot = t + p * 256;
            if (slot < 536) {
                int r  = slot >> 3;
                int c4 = (slot & 7) * 4;
                float4 v4 = make_float4(0.f, 0.f, 0.f, 0.f);
                if (!(lhead && r < 3))
                    v4 = *(const float4*)(xz + (size_t)(m0 - 3 + r) * NIN + k0 + c4);
                *(float4*)&sX[r][c4] = v4;
            }
        }
        __syncthreads();

        {
            float xvv[4][8];
#pragma unroll
            for (int k = 0; k < 4; ++k) {
                *(float4*)&xvv[k][0] = *(float4*)&sX[row + k][kq8];
                *(float4*)&xvv[k][4] = *(float4*)&sX[row + k][kq8 + 4];
            }
            float v[8];
            *(float4*)(v)     = *(float4*)&cbL[k0 + kq8];
            *(float4*)(v + 4) = *(float4*)&cbL[k0 + kq8 + 4];
#pragma unroll
            for (int j = 0; j < 8; ++j) {
                float4 cwj = *(float4*)&cwL[k0 + kq8 + j][0];
                const float* cwp = (const float*)&cwj;
#pragma unroll
                for (int k = 0; k < 4; ++k)
                    v[j] = fmaf(xvv[k][j], cwp[k], v[j]);
                v[j] = v[j] * sigmoid_f(v[j]);
            }
            short8 hi, lo;
#pragma unroll
            for (int j = 0; j < 8; ++j) {
                unsigned int h = bf16_rne(v[j]);
                float r = v[j] - __uint_as_float(h << 16);
                hi[j] = (short)h;
                lo[j] = (short)bf16_rne(r);
            }
            *(short8*)&sA[row][kq8]      = hi;
            *(short8*)&sA[64 + row][kq8] = lo;
            if (write_xc) {
                float* pxc = xc + (size_t)(m0 + row) * DI + k0 + kq8;
                *(float4*)(pxc)     = *(float4*)(v);
                *(float4*)(pxc + 4) = *(float4*)(v + 4);
            }
            const size_t boff = (size_t)(n0 + row) * DM + k0 + kq8;
            *(short8*)&sB[row][kq8]      = *(const short8*)(BT_hi + boff);
            *(short8*)&sB[64 + row][kq8] = *(const short8*)(BT_lo + boff);
        }
        __syncthreads();

        short8 ah[2], al[2], bh[2], bl[2];
#pragma unroll
        for (int mi = 0; mi < 2; ++mi) {
            int mr = mwb + mi * 16 + fr;
            ah[mi] = *(const short8*)&sA[mr][q * 8];
            al[mi] = *(const short8*)&sA[64 + mr][q * 8];
        }
#pragma unroll
        for (int ni = 0; ni < 2; ++ni) {
            int nr = nwb + ni * 16 + fr;
            bh[ni] = *(const short8*)&sB[nr][q * 8];
            bl[ni] = *(const short8*)&sB[64 + nr][q * 8];
        }
#pragma unroll
        for (int mi = 0; mi < 2; ++mi)
#pragma unroll
            for (int ni = 0; ni < 2; ++ni) {
                acc[mi][ni] = __builtin_amdgcn_mfma_f32_16x16x32_bf16(ah[mi], bh[ni], acc[mi][ni], 0, 0, 0);
                acc[mi][ni] = __builtin_amdgcn_mfma_f32_16x16x32_bf16(ah[mi], bl[ni], acc[mi][ni], 0, 0, 0);
                acc[mi][ni] = __builtin_amdgcn_mfma_f32_16x16x32_bf16(al[mi], bh[ni], acc[mi][ni], 0, 0, 0);
            }
        __syncthreads();
    }

#pragma unroll
    for (int mi = 0; mi < 2; ++mi)
#pragma unroll
        for (int ni = 0; ni < 2; ++ni) {
            int n = n0 + nwb + ni * 16 + fr;
            if (n < 256) {
                float bd = b_dt[n];
#pragma unroll
                for (int r = 0; r < 4; ++r) {
                    int m = m0 + mwb + mi * 16 + q * 4 + r;
                    float a2 = acc[mi][ni][r] + bd;
                    float sp = fmaxf(a2, 0.f) + __logf(1.f + __expf(-fabsf(a2)));
                    dt[(size_t)m * DI + n] = sp;
                }
            } else if (n < 288) {
#pragma unroll
                for (int r = 0; r < 4; ++r) {
                    int m = m0 + mwb + mi * 16 + q * 4 + r;
                    bc[(size_t)m * 32 + (n - 256)] = acc[mi][ni][r];
                }
            }
        }
}

// ---------------- scan phase A: local final F + per-chunk dt-sum ----------------
__global__ __launch_bounds__(256) void scan_a_k(const float* __restrict__ dt,
                                                const float* __restrict__ xc,
                                                const float* __restrict__ bc,
                                                const float* __restrict__ A_log,
                                                float* __restrict__ sumdt,
                                                float* __restrict__ Fst) {
    __shared__ float Bl[LCHUNK][16];
    const int blk   = blockIdx.x;
    const int b     = blk / NCHUNK;
    const int chunk = blk % NCHUNK;
    const int d     = threadIdx.x;
    const int l0    = chunk * LCHUNK;

    if (d < LCHUNK * 4) {
        int l = d >> 2, q = d & 3;
        *(float4*)(&Bl[l][q * 4]) =
            *(const float4*)(bc + (size_t)(b * LSEQ + l0 + l) * 32 + q * 4);
    }
    float Ads2[16];
#pragma unroll
    for (int s = 0; s < 16; ++s) Ads2[s] = -expf(A_log[d * DS + s]) * LOG2E;
    __syncthreads();

    float h[16];
#pragma unroll
    for (int s = 0; s < 16; ++s) h[s] = 0.f;
    float sd = 0.f;

    const float* dtp = dt + ((size_t)b * LSEQ + l0) * DI + d;
    const float* xcp = xc + ((size_t)b * LSEQ + l0) * DI + d;

#pragma unroll 4
    for (int i = 0; i < LCHUNK; ++i) {
        float dtv = dtp[(size_t)i * DI];
        float xcv = xcp[(size_t)i * DI];
        float du  = dtv * xcv;
        sd += dtv;
        float4 b0 = *(float4*)(&Bl[i][0]);
        float4 b1 = *(float4*)(&Bl[i][4]);
        float4 b2 = *(float4*)(&Bl[i][8]);
        float4 b3 = *(float4*)(&Bl[i][12]);
        float bv[16] = {b0.x,b0.y,b0.z,b0.w, b1.x,b1.y,b1.z,b1.w,
                        b2.x,b2.y,b2.z,b2.w, b3.x,b3.y,b3.z,b3.w};
#pragma unroll
        for (int s = 0; s < 16; ++s) {
            float a = exp2_f(dtv * Ads2[s]);
            h[s] = fmaf(h[s], a, du * bv[s]);
        }
    }
    size_t base = ((size_t)(b * DI + d) * NCHUNK + chunk) * DS;
#pragma unroll
    for (int q = 0; q < 4; ++q)
        *(float4*)(Fst + base + q * 4) = make_float4(h[q*4], h[q*4+1], h[q*4+2], h[q*4+3]);
    sumdt[(size_t)(b * DI + d) * NCHUNK + chunk] = sd;
}

// ---------------- scan phase B: two-level chunk-prefix, one block per (b,d) ----------------
// 512 blocks x 256 threads: thread (s = t&15, g = t>>4) owns 16 chunks.
__global__ __launch_bounds__(256) void scan_b_k(const float* __restrict__ sumdt,
                                                const float* __restrict__ A_log,
                                                float* __restrict__ Fst) {
    __shared__ float Pg[16][17], Fg[16][17], carryG[16][17];
    const int bd = blockIdx.x;            // b*DI + d
    const int d  = bd & (DI - 1);
    const int t  = threadIdx.x;
    const int s  = t & 15;
    const int g  = t >> 4;
    const float Ads2 = -expf(A_log[d * DS + s]) * LOG2E;
    const float* sdp = sumdt + (size_t)bd * NCHUNK;
    const size_t base = (size_t)bd * NCHUNK * DS + s;

    // level 1: compose this thread's 16 chunks into affine (P,F); cache per-chunk P,F
    float Pc[16], Fc[16];
    float P = 1.f, F = 0.f;
#pragma unroll
    for (int i = 0; i < 16; ++i) {
        int c = g * 16 + i;
        float p = exp2_f(sdp[c] * Ads2);
        float f = Fst[base + (size_t)c * DS];
        Pc[i] = p; Fc[i] = f;
        F = fmaf(p, F, f);
        P *= p;
    }
    Pg[g][s] = P;
    Fg[g][s] = F;
    __syncthreads();

    // level 2: serial scan over the 16 groups (16 threads, one per s)
    if (g == 0) {
        float st = 0.f;
#pragma unroll
        for (int gg = 0; gg < 16; ++gg) {
            carryG[gg][s] = st;
            st = fmaf(Pg[gg][s], st, Fg[gg][s]);
        }
    }
    __syncthreads();

    // level 3: replay with carry-in, writing per-chunk carries
    float st = carryG[g][s];
#pragma unroll
    for (int i = 0; i < 16; ++i) {
        int c = g * 16 + i;
        Fst[base + (size_t)c * DS] = st;
        st = fmaf(Pc[i], st, Fc[i]);
    }
}

// ---------------- scan phase C ----------------
__global__ __launch_bounds__(256) void scan_c_k(const float* __restrict__ dt,
                                                const float* __restrict__ xc,
                                                const float* __restrict__ bc,
                                                const float* __restrict__ xz,
                                                const float* __restrict__ A_log,
                                                const float* __restrict__ Dw,
                                                const float* __restrict__ carry,
                                                float* __restrict__ y) {
    __shared__ float BC[LCHUNK][32];
    const int blk   = blockIdx.x;
    const int b     = blk / NCHUNK;
    const int chunk = blk % NCHUNK;
    const int d     = threadIdx.x;
    const int l0    = chunk * LCHUNK;

    if (d < LCHUNK * 8) {
        int l = d >> 3, q = d & 7;
        *(float4*)(&BC[l][q * 4]) =
            *(const float4*)(bc + (size_t)(b * LSEQ + l0 + l) * 32 + q * 4);
    }
    float Ads2[16];
#pragma unroll
    for (int s = 0; s < 16; ++s) Ads2[s] = -expf(A_log[d * DS + s]) * LOG2E;
    const float Dd = Dw[d];

    float h[16];
    size_t cbase = ((size_t)(b * DI + d) * NCHUNK + chunk) * DS;
#pragma unroll
    for (int q = 0; q < 4; ++q) {
        float4 c4 = *(const float4*)(carry + cbase + q * 4);
        h[q*4] = c4.x; h[q*4+1] = c4.y; h[q*4+2] = c4.z; h[q*4+3] = c4.w;
    }
    __syncthreads();

    const float* dtp = dt + ((size_t)b * LSEQ + l0) * DI + d;
    const float* xcp = xc + ((size_t)b * LSEQ + l0) * DI + d;
    const float* zp  = xz + ((size_t)b * LSEQ + l0) * NIN + DI + d;   // already silu'd
    float* yout      = y  + ((size_t)b * LSEQ + l0) * DI + d;

#pragma unroll 4
    for (int i = 0; i < LCHUNK; ++i) {
        float dtv = dtp[(size_t)i * DI];
        float xcv = xcp[(size_t)i * DI];
        float zs  = zp[(size_t)i * NIN];
        float du  = dtv * xcv;
        float4 b0 = *(float4*)(&BC[i][0]);
        float4 b1 = *(float4*)(&BC[i][4]);
        float4 b2 = *(float4*)(&BC[i][8]);
        float4 b3 = *(float4*)(&BC[i][12]);
        float4 c0 = *(float4*)(&BC[i][16]);
        float4 c1 = *(float4*)(&BC[i][20]);
        float4 c2 = *(float4*)(&BC[i][24]);
        float4 c3 = *(float4*)(&BC[i][28]);
        float bv[16] = {b0.x,b0.y,b0.z,b0.w, b1.x,b1.y,b1.z,b1.w,
                        b2.x,b2.y,b2.z,b2.w, b3.x,b3.y,b3.z,b3.w};
        float cv[16] = {c0.x,c0.y,c0.z,c0.w, c1.x,c1.y,c1.z,c1.w,
                        c2.x,c2.y,c2.z,c2.w, c3.x,c3.y,c3.z,c3.w};
        float yv = 0.f;
#pragma unroll
        for (int s = 0; s < 16; ++s) {
            float a = exp2_f(dtv * Ads2[s]);
            h[s] = fmaf(h[s], a, du * bv[s]);
            yv = fmaf(h[s], cv[s], yv);
        }
        float yf = fmaf(xcv, Dd, yv);
        yout[(size_t)i * DI] = yf * zs;
    }
}

// ---------------- gemm_out (MFMA bf16x3): out[b,c,l] = sum_d y[b,l,d] * W_out[d,c] ----------------
__global__ __launch_bounds__(256) void gemm_out_k(const float* __restrict__ y,
                                                  const unsigned short* __restrict__ WT_hi,
                                                  const unsigned short* __restrict__ WT_lo,
                                                  float* __restrict__ out) {
    __shared__ unsigned short sA[128][40];
    __shared__ unsigned short sB[128][40];
    const int b  = blockIdx.z;
    const int m0 = blockIdx.y * 64;    // l
    const int n0 = blockIdx.x * 64;    // c
    const int t  = threadIdx.x;
    const int w    = t >> 6;
    const int lane = t & 63;
    const int mwb = (w & 1) * 32;
    const int nwb = (w >> 1) * 32;
    const int fr  = lane & 15;
    const int q   = lane >> 4;

    const int row = t >> 2;
    const int kq8 = (t & 3) * 8;

    floatx4 acc[2][2];
#pragma unroll
    for (int mi = 0; mi < 2; ++mi)
#pragma unroll
        for (int ni = 0; ni < 2; ++ni) acc[mi][ni] = (floatx4){0.f, 0.f, 0.f, 0.f};

    for (int k0 = 0; k0 < DI; k0 += 32) {
        {
            const float* pa = y + ((size_t)b * LSEQ + m0 + row) * DI + k0 + kq8;
            float v[8];
            *(float4*)(v)     = *(const float4*)(pa);
            *(float4*)(v + 4) = *(const float4*)(pa + 4);
            short8 hi, lo;
#pragma unroll
            for (int j = 0; j < 8; ++j) {
                unsigned int h = bf16_rne(v[j]);
                float r = v[j] - __uint_as_float(h << 16);
                hi[j] = (short)h;
                lo[j] = (short)bf16_rne(r);
            }
            *(short8*)&sA[row][kq8]      = hi;
            *(short8*)&sA[64 + row][kq8] = lo;

            const size_t boff = (size_t)(n0 + row) * DM + k0 + kq8;
            *(short8*)&sB[row][kq8]      = *(const short8*)(WT_hi + boff);
            *(short8*)&sB[64 + row][kq8] = *(const short8*)(WT_lo + boff);
        }
        __syncthreads();

        short8 ah[2], al[2], bh[2], bl[2];
#pragma unroll
        for (int mi = 0; mi < 2; ++mi) {
            int mr = mwb + mi * 16 + fr;
            ah[mi] = *(const short8*)&sA[mr][q * 8];
            al[mi] = *(const short8*)&sA[64 + mr][q * 8];
        }
#pragma unroll
        for (int ni = 0; ni < 2; ++ni) {
            int nr = nwb + ni * 16 + fr;
            bh[ni] = *(const short8*)&sB[nr][q * 8];
            bl[ni] = *(const short8*)&sB[64 + nr][q * 8];
        }
#pragma unroll
        for (int mi = 0; mi < 2; ++mi)
#pragma unroll
            for (int ni = 0; ni < 2; ++ni) {
                acc[mi][ni] = __builtin_amdgcn_mfma_f32_16x16x32_bf16(ah[mi], bh[ni], acc[mi][ni], 0, 0, 0);
                acc[mi][ni] = __builtin_amdgcn_mfma_f32_16x16x32_bf16(ah[mi], bl[ni], acc[mi][ni], 0, 0, 0);
                acc[mi][ni] = __builtin_amdgcn_mfma_f32_16x16x32_bf16(al[mi], bh[ni], acc[mi][ni], 0, 0, 0);
            }
        __syncthreads();
    }

#pragma unroll
    for (int mi = 0; mi < 2; ++mi)
#pragma unroll
        for (int ni = 0; ni < 2; ++ni) {
            int c = n0 + nwb + ni * 16 + fr;
            float* op = out + ((size_t)b * DM + c) * LSEQ + m0 + mwb + mi * 16 + q * 4;
            *(float4*)op = make_float4(acc[mi][ni][0], acc[mi][ni][1],
                                       acc[mi][ni][2], acc[mi][ni][3]);
        }
}

extern "C" void kernel_launch(void* const* d_in, const int* in_sizes, int n_in,
                              void* d_out, int out_size, void* d_ws, size_t ws_size,
                              hipStream_t stream) {
    const float* x      = (const float*)d_in[0];
    const float* W_in   = (const float*)d_in[1];
    const float* conv_w = (const float*)d_in[2];
    const float* conv_b = (const float*)d_in[3];
    const float* W_x    = (const float*)d_in[4];
    const float* W_dt   = (const float*)d_in[5];
    const float* b_dt   = (const float*)d_in[6];
    const float* A_log  = (const float*)d_in[7];
    const float* Dw     = (const float*)d_in[8];
    const float* W_out  = (const float*)d_in[9];
    float* out = (float*)d_out;

    float* ws    = (float*)d_ws;
    float* xz    = ws;                    // B*L*512            = 4,194,304
    float* xc    = xz + 4194304;          // B*L*256            = 2,097,152
    float* bc    = xc + 2097152;          // B*L*32             =   262,144
    float* dtb   = bc + 262144;           // B*L*256            = 2,097,152
    float* sumdt = dtb + 2097152;         // B*DI*NCHUNK        =   131,072
    float* Fst   = sumdt + 131072;        // B*DI*NCHUNK*DS     = 2,097,152
    float* yb    = Fst + 2097152;         // B*L*DI             = 2,097,152
    unsigned short* WinT_hi  = (unsigned short*)(yb + 2097152);   // 512*256
    unsigned short* WinT_lo  = WinT_hi + 131072;
    unsigned short* WoutT_hi = WinT_lo + 131072;                  // 256*256
    unsigned short* WoutT_lo = WoutT_hi + 65536;
    unsigned short* BcatT_hi = WoutT_lo + 65536;                  // 320*256
    unsigned short* BcatT_lo = BcatT_hi + 81920;

    setup_k    <<<dim3(256), 512, 0, stream>>>(W_in, W_out, W_x, W_dt,
                                               WinT_hi, WinT_lo, WoutT_hi, WoutT_lo,
                                               BcatT_hi, BcatT_lo);
    gemm_in_k  <<<dim3(8, 64, BSZ), 256, 0, stream>>>(x, WinT_hi, WinT_lo, xz);
    gemm_x2c_k <<<dim3(5, 128), 256, 0, stream>>>(xz, conv_w, conv_b,
                                                  BcatT_hi, BcatT_lo, b_dt, xc, dtb, bc);
    scan_a_k   <<<dim3(BSZ * NCHUNK), 256, 0, stream>>>(dtb, xc, bc, A_log, sumdt, Fst);
    scan_b_k   <<<dim3(BSZ * DI), 256, 0, stream>>>(sumdt, A_log, Fst);
    scan_c_k   <<<dim3(BSZ * NCHUNK), 256, 0, stream>>>(dtb, xc, bc, xz, A_log, Dw, Fst, yb);
    gemm_out_k <<<dim3(4, 64, BSZ), 256, 0, stream>>>(yb, WoutT_hi, WoutT_lo, out);
}

// Round 15
// 160.000 us; speedup vs baseline: 1.0787x; 1.0166x over previous
//
#include <hip/hip_runtime.h>
#include <math.h>

#define BSZ 2
#define LSEQ 4096
#define DM 256      // d_model
#define DI 256      // d_inner
#define DS 16       // d_state
#define DR 16       // dt_rank
#define NIN 512     // 2*DI
#define NCHUNK 256
#define LCHUNK 16
#define NB2 320     // padded Bcat width (288 real: 256 dt + 32 bc)

typedef __attribute__((ext_vector_type(8))) short short8;
typedef __attribute__((ext_vector_type(4))) float floatx4;

__device__ __forceinline__ float sigmoid_f(float v) {
    return __builtin_amdgcn_rcpf(1.0f + __expf(-v));
}

__device__ __forceinline__ float exp2_f(float v) {
    return __builtin_amdgcn_exp2f(v);
}

__device__ __forceinline__ unsigned int bf16_rne(float v) {
    unsigned int u = __float_as_uint(v);
    return (u + 0x7FFFu + ((u >> 16) & 1u)) >> 16;
}

#define LOG2E 1.44269504088896340736f

// ---------------- setup: split W_in/W_out transposed + build BcatT + Ads2 table ----------------
__global__ __launch_bounds__(512) void setup_k(const float* __restrict__ W_in,
                                               const float* __restrict__ W_out,
                                               const float* __restrict__ W_x,
                                               const float* __restrict__ W_dt,
                                               const float* __restrict__ A_log,
                                               unsigned short* __restrict__ WinT_hi,
                                               unsigned short* __restrict__ WinT_lo,
                                               unsigned short* __restrict__ WoutT_hi,
                                               unsigned short* __restrict__ WoutT_lo,
                                               unsigned short* __restrict__ BcatT_hi,
                                               unsigned short* __restrict__ BcatT_lo,
                                               float* __restrict__ Ads2) {
    __shared__ float wr[16];
    const int k = blockIdx.x;          // 0..255
    const int t = threadIdx.x;         // 0..511
    if (t < 16) wr[t] = W_x[(size_t)k * 48 + t];
    if (t >= 496) {                    // 16 threads: Ads2 row for d=k
        int s = t - 496;
        Ads2[k * DS + s] = -expf(A_log[k * DS + s]) * LOG2E;
    }
    {
        float v = W_in[(size_t)k * NIN + t];
        unsigned int h = bf16_rne(v);
        float r = v - __uint_as_float(h << 16);
        WinT_hi[(size_t)t * DM + k] = (unsigned short)h;
        WinT_lo[(size_t)t * DM + k] = (unsigned short)bf16_rne(r);
    }
    if (t < DM) {
        float v = W_out[(size_t)k * DM + t];
        unsigned int h = bf16_rne(v);
        float r = v - __uint_as_float(h << 16);
        WoutT_hi[(size_t)t * DM + k] = (unsigned short)h;
        WoutT_lo[(size_t)t * DM + k] = (unsigned short)bf16_rne(r);
    }
    __syncthreads();
    if (t < NB2) {
        float v;
        if (t < 256) {
            float acc = 0.f;
#pragma unroll
            for (int r = 0; r < 16; ++r) acc = fmaf(wr[r], W_dt[r * DI + t], acc);
            v = acc;
        } else if (t < 288) {
            v = W_x[(size_t)k * 48 + 16 + (t - 256)];
        } else {
            v = 0.f;
        }
        unsigned int h = bf16_rne(v);
        float r = v - __uint_as_float(h << 16);
        BcatT_hi[(size_t)t * DM + k] = (unsigned short)h;
        BcatT_lo[(size_t)t * DM + k] = (unsigned short)bf16_rne(r);
    }
}

// ---------------- gemm_in (MFMA bf16x3): xz = x^T @ W_in; z-half gets SiLU in epilogue ----------------
__global__ __launch_bounds__(256) void gemm_in_k(const float* __restrict__ x,
                                                 const unsigned short* __restrict__ WT_hi,
                                                 const unsigned short* __restrict__ WT_lo,
                                                 float* __restrict__ xz) {
    __shared__ unsigned short sA[128][40];
    __shared__ unsigned short sB[128][40];
    const int b  = blockIdx.z;
    const int m0 = blockIdx.y * 64;
    const int n0 = blockIdx.x * 64;
    const int t  = threadIdx.x;
    const int w    = t >> 6;
    const int lane = t & 63;
    const int kp = t & 15;
    const int g  = t >> 4;

    const int mwb = (w & 1) * 32;
    const int nwb = (w >> 1) * 32;
    const int fr  = lane & 15;
    const int q   = lane >> 4;

    const int brow = t >> 2;
    const int bkq8 = (t & 3) * 8;

    floatx4 acc[2][2];
#pragma unroll
    for (int mi = 0; mi < 2; ++mi)
#pragma unroll
        for (int ni = 0; ni < 2; ++ni) acc[mi][ni] = (floatx4){0.f, 0.f, 0.f, 0.f};

    for (int k0 = 0; k0 < DM; k0 += 32) {
        {
            const float* pa = x + ((size_t)b * DM + k0 + 2 * kp) * LSEQ + m0 + 4 * g;
            float4 fa0 = *(const float4*)(pa);
            float4 fa1 = *(const float4*)(pa + LSEQ);
            const float* a0 = (const float*)&fa0;
            const float* a1 = (const float*)&fa1;
#pragma unroll
            for (int j = 0; j < 4; ++j) {
                int m = 4 * g + j;
                unsigned int h0 = bf16_rne(a0[j]);
                unsigned int h1 = bf16_rne(a1[j]);
                float r0 = a0[j] - __uint_as_float(h0 << 16);
                float r1 = a1[j] - __uint_as_float(h1 << 16);
                unsigned int l0 = bf16_rne(r0);
                unsigned int l1 = bf16_rne(r1);
                *(unsigned int*)&sA[m][2 * kp]      = h0 | (h1 << 16);
                *(unsigned int*)&sA[64 + m][2 * kp] = l0 | (l1 << 16);
            }
            const size_t boff = (size_t)(n0 + brow) * DM + k0 + bkq8;
            *(short8*)&sB[brow][bkq8]      = *(const short8*)(WT_hi + boff);
            *(short8*)&sB[64 + brow][bkq8] = *(const short8*)(WT_lo + boff);
        }
        __syncthreads();

        short8 ah[2], al[2], bh[2], bl[2];
#pragma unroll
        for (int mi = 0; mi < 2; ++mi) {
            int mr = mwb + mi * 16 + fr;
            ah[mi] = *(const short8*)&sA[mr][q * 8];
            al[mi] = *(const short8*)&sA[64 + mr][q * 8];
        }
#pragma unroll
        for (int ni = 0; ni < 2; ++ni) {
            int nr = nwb + ni * 16 + fr;
            bh[ni] = *(const short8*)&sB[nr][q * 8];
            bl[ni] = *(const short8*)&sB[64 + nr][q * 8];
        }
#pragma unroll
        for (int mi = 0; mi < 2; ++mi)
#pragma unroll
            for (int ni = 0; ni < 2; ++ni) {
                acc[mi][ni] = __builtin_amdgcn_mfma_f32_16x16x32_bf16(ah[mi], bh[ni], acc[mi][ni], 0, 0, 0);
                acc[mi][ni] = __builtin_amdgcn_mfma_f32_16x16x32_bf16(ah[mi], bl[ni], acc[mi][ni], 0, 0, 0);
                acc[mi][ni] = __builtin_amdgcn_mfma_f32_16x16x32_bf16(al[mi], bh[ni], acc[mi][ni], 0, 0, 0);
            }
        __syncthreads();
    }

    const bool isz = (n0 >= 256);   // z-half: store silu(z)
#pragma unroll
    for (int mi = 0; mi < 2; ++mi)
#pragma unroll
        for (int ni = 0; ni < 2; ++ni) {
#pragma unroll
            for (int r = 0; r < 4; ++r) {
                int m = m0 + mwb + mi * 16 + q * 4 + r;
                int n = n0 + nwb + ni * 16 + fr;
                float v = acc[mi][ni][r];
                if (isz) v = v * sigmoid_f(v);
                xz[((size_t)b * LSEQ + m) * NIN + n] = v;
            }
        }
}

// ---------------- gemm_x2c (MFMA bf16x3, conv+SiLU as coalesced LDS producer phase) ----------------
__global__ __launch_bounds__(256) void gemm_x2c_k(const float* __restrict__ xz,
                                                  const float* __restrict__ conv_w,
                                                  const float* __restrict__ conv_b,
                                                  const unsigned short* __restrict__ BT_hi,
                                                  const unsigned short* __restrict__ BT_lo,
                                                  const float* __restrict__ b_dt,
                                                  float* __restrict__ xc,
                                                  float* __restrict__ dt,
                                                  float* __restrict__ bc) {
    __shared__ unsigned short sA[128][40];
    __shared__ unsigned short sB[128][40];
    __shared__ float sX[67][36];
    __shared__ float cwL[256][4];
    __shared__ float cbL[256];
    const int m0 = blockIdx.y * 64;
    const int n0 = blockIdx.x * 64;
    const int t  = threadIdx.x;
    const int w    = t >> 6;
    const int lane = t & 63;
    const int mwb = (w & 1) * 32;
    const int nwb = (w >> 1) * 32;
    const int fr  = lane & 15;
    const int q   = lane >> 4;

    const int row = t >> 2;           // 0..63
    const int kq8 = (t & 3) * 8;      // 0,8,16,24
    const bool write_xc = (blockIdx.x == 0);
    const bool lhead = ((m0 & (LSEQ - 1)) == 0);

    *(float4*)&cwL[t][0] = *(const float4*)(conv_w + t * 4);
    cbL[t] = conv_b[t];

    floatx4 acc[2][2];
#pragma unroll
    for (int mi = 0; mi < 2; ++mi)
#pragma unroll
        for (int ni = 0; ni < 2; ++ni) acc[mi][ni] = (floatx4){0.f, 0.f, 0.f, 0.f};

    for (int k0 = 0; k0 < DI; k0 += 32) {
#pragma unroll
        for (int p = 0; p < 3; ++p) {
            int slot = t + p * 256;
            if (slot < 536) {
                int r  = slot >> 3;
                int c4 = (slot & 7) * 4;
                float4 v4 = make_float4(0.f, 0.f, 0.f, 0.f);
                if (!(lhead && r < 3))
                    v4 = *(const float4*)(xz + (size_t)(m0 - 3 + r) * NIN + k0 + c4);
                *(float4*)&sX[r][c4] = v4;
            }
        }
        __syncthreads();

        {
            float xvv[4][8];
#pragma unroll
            for (int k = 0; k < 4; ++k) {
                *(float4*)&xvv[k][0] = *(float4*)&sX[row + k][kq8];
                *(float4*)&xvv[k][4] = *(float4*)&sX[row + k][kq8 + 4];
            }
            float v[8];
            *(float4*)(v)     = *(float4*)&cbL[k0 + kq8];
            *(float4*)(v + 4) = *(float4*)&cbL[k0 + kq8 + 4];
#pragma unroll
            for (int j = 0; j < 8; ++j) {
                float4 cwj = *(float4*)&cwL[k0 + kq8 + j][0];
                const float* cwp = (const float*)&cwj;
#pragma unroll
                for (int k = 0; k < 4; ++k)
                    v[j] = fmaf(xvv[k][j], cwp[k], v[j]);
                v[j] = v[j] * sigmoid_f(v[j]);
            }
            short8 hi, lo;
#pragma unroll
            for (int j = 0; j < 8; ++j) {
                unsigned int h = bf16_rne(v[j]);
                float r = v[j] - __uint_as_float(h << 16);
                hi[j] = (short)h;
                lo[j] = (short)bf16_rne(r);
            }
            *(short8*)&sA[row][kq8]      = hi;
            *(short8*)&sA[64 + row][kq8] = lo;
            if (write_xc) {
                float* pxc = xc + (size_t)(m0 + row) * DI + k0 + kq8;
                *(float4*)(pxc)     = *(float4*)(v);
                *(float4*)(pxc + 4) = *(float4*)(v + 4);
            }
            const size_t boff = (size_t)(n0 + row) * DM + k0 + kq8;
            *(short8*)&sB[row][kq8]      = *(const short8*)(BT_hi + boff);
            *(short8*)&sB[64 + row][kq8] = *(const short8*)(BT_lo + boff);
        }
        __syncthreads();

        short8 ah[2], al[2], bh[2], bl[2];
#pragma unroll
        for (int mi = 0; mi < 2; ++mi) {
            int mr = mwb + mi * 16 + fr;
            ah[mi] = *(const short8*)&sA[mr][q * 8];
            al[mi] = *(const short8*)&sA[64 + mr][q * 8];
        }
#pragma unroll
        for (int ni = 0; ni < 2; ++ni) {
            int nr = nwb + ni * 16 + fr;
            bh[ni] = *(const short8*)&sB[nr][q * 8];
            bl[ni] = *(const short8*)&sB[64 + nr][q * 8];
        }
#pragma unroll
        for (int mi = 0; mi < 2; ++mi)
#pragma unroll
            for (int ni = 0; ni < 2; ++ni) {
                acc[mi][ni] = __builtin_amdgcn_mfma_f32_16x16x32_bf16(ah[mi], bh[ni], acc[mi][ni], 0, 0, 0);
                acc[mi][ni] = __builtin_amdgcn_mfma_f32_16x16x32_bf16(ah[mi], bl[ni], acc[mi][ni], 0, 0, 0);
                acc[mi][ni] = __builtin_amdgcn_mfma_f32_16x16x32_bf16(al[mi], bh[ni], acc[mi][ni], 0, 0, 0);
            }
        __syncthreads();
    }

#pragma unroll
    for (int mi = 0; mi < 2; ++mi)
#pragma unroll
        for (int ni = 0; ni < 2; ++ni) {
            int n = n0 + nwb + ni * 16 + fr;
            if (n < 256) {
                float bd = b_dt[n];
#pragma unroll
                for (int r = 0; r < 4; ++r) {
                    int m = m0 + mwb + mi * 16 + q * 4 + r;
                    float a2 = acc[mi][ni][r] + bd;
                    float sp = fmaxf(a2, 0.f) + __logf(1.f + __expf(-fabsf(a2)));
                    dt[(size_t)m * DI + n] = sp;
                }
            } else if (n < 288) {
#pragma unroll
                for (int r = 0; r < 4; ++r) {
                    int m = m0 + mwb + mi * 16 + q * 4 + r;
                    bc[(size_t)m * 32 + (n - 256)] = acc[mi][ni][r];
                }
            }
        }
}

// ---------------- scan phase A: local final F + per-chunk dt-sum ----------------
__global__ __launch_bounds__(256) void scan_a_k(const float* __restrict__ dt,
                                                const float* __restrict__ xc,
                                                const float* __restrict__ bc,
                                                const float* __restrict__ Ads2t,
                                                float* __restrict__ sumdt,
                                                float* __restrict__ Fst) {
    __shared__ float Bl[LCHUNK][16];
    const int blk   = blockIdx.x;
    const int b     = blk / NCHUNK;
    const int chunk = blk % NCHUNK;
    const int d     = threadIdx.x;
    const int l0    = chunk * LCHUNK;

    if (d < LCHUNK * 4) {
        int l = d >> 2, q = d & 3;
        *(float4*)(&Bl[l][q * 4]) =
            *(const float4*)(bc + (size_t)(b * LSEQ + l0 + l) * 32 + q * 4);
    }
    float Ads2[16];
#pragma unroll
    for (int q = 0; q < 4; ++q)
        *(float4*)(Ads2 + q * 4) = *(const float4*)(Ads2t + d * DS + q * 4);
    __syncthreads();

    float h[16];
#pragma unroll
    for (int s = 0; s < 16; ++s) h[s] = 0.f;
    float sd = 0.f;

    const float* dtp = dt + ((size_t)b * LSEQ + l0) * DI + d;
    const float* xcp = xc + ((size_t)b * LSEQ + l0) * DI + d;

#pragma unroll 4
    for (int i = 0; i < LCHUNK; ++i) {
        float dtv = dtp[(size_t)i * DI];
        float xcv = xcp[(size_t)i * DI];
        float du  = dtv * xcv;
        sd += dtv;
        float4 b0 = *(float4*)(&Bl[i][0]);
        float4 b1 = *(float4*)(&Bl[i][4]);
        float4 b2 = *(float4*)(&Bl[i][8]);
        float4 b3 = *(float4*)(&Bl[i][12]);
        float bv[16] = {b0.x,b0.y,b0.z,b0.w, b1.x,b1.y,b1.z,b1.w,
                        b2.x,b2.y,b2.z,b2.w, b3.x,b3.y,b3.z,b3.w};
#pragma unroll
        for (int s = 0; s < 16; ++s) {
            float a = exp2_f(dtv * Ads2[s]);
            h[s] = fmaf(h[s], a, du * bv[s]);
        }
    }
    size_t base = ((size_t)(b * DI + d) * NCHUNK + chunk) * DS;
#pragma unroll
    for (int q = 0; q < 4; ++q)
        *(float4*)(Fst + base + q * 4) = make_float4(h[q*4], h[q*4+1], h[q*4+2], h[q*4+3]);
    sumdt[(size_t)(b * DI + d) * NCHUNK + chunk] = sd;
}

// ---------------- scan phase B: two-level chunk-prefix, one block per (b,d) ----------------
__global__ __launch_bounds__(256) void scan_b_k(const float* __restrict__ sumdt,
                                                const float* __restrict__ Ads2t,
                                                float* __restrict__ Fst) {
    __shared__ float Pg[16][17], Fg[16][17], carryG[16][17];
    const int bd = blockIdx.x;            // b*DI + d
    const int d  = bd & (DI - 1);
    const int t  = threadIdx.x;
    const int s  = t & 15;
    const int g  = t >> 4;
    const float Ads2 = Ads2t[d * DS + s];
    const float* sdp = sumdt + (size_t)bd * NCHUNK;
    const size_t base = (size_t)bd * NCHUNK * DS + s;

    float Pc[16], Fc[16];
    float P = 1.f, F = 0.f;
#pragma unroll
    for (int i = 0; i < 16; ++i) {
        int c = g * 16 + i;
        float p = exp2_f(sdp[c] * Ads2);
        float f = Fst[base + (size_t)c * DS];
        Pc[i] = p; Fc[i] = f;
        F = fmaf(p, F, f);
        P *= p;
    }
    Pg[g][s] = P;
    Fg[g][s] = F;
    __syncthreads();

    if (g == 0) {
        float st = 0.f;
#pragma unroll
        for (int gg = 0; gg < 16; ++gg) {
            carryG[gg][s] = st;
            st = fmaf(Pg[gg][s], st, Fg[gg][s]);
        }
    }
    __syncthreads();

    float st = carryG[g][s];
#pragma unroll
    for (int i = 0; i < 16; ++i) {
        int c = g * 16 + i;
        Fst[base + (size_t)c * DS] = st;
        st = fmaf(Pc[i], st, Fc[i]);
    }
}

// ---------------- scan phase C: produce y pre-split bf16 hi/lo ----------------
__global__ __launch_bounds__(256) void scan_c_k(const float* __restrict__ dt,
                                                const float* __restrict__ xc,
                                                const float* __restrict__ bc,
                                                const float* __restrict__ xz,
                                                const float* __restrict__ Ads2t,
                                                const float* __restrict__ Dw,
                                                const float* __restrict__ carry,
                                                unsigned short* __restrict__ yh,
                                                unsigned short* __restrict__ yl) {
    __shared__ float BC[LCHUNK][32];
    const int blk   = blockIdx.x;
    const int b     = blk / NCHUNK;
    const int chunk = blk % NCHUNK;
    const int d     = threadIdx.x;
    const int l0    = chunk * LCHUNK;

    if (d < LCHUNK * 8) {
        int l = d >> 3, q = d & 7;
        *(float4*)(&BC[l][q * 4]) =
            *(const float4*)(bc + (size_t)(b * LSEQ + l0 + l) * 32 + q * 4);
    }
    float Ads2[16];
#pragma unroll
    for (int q = 0; q < 4; ++q)
        *(float4*)(Ads2 + q * 4) = *(const float4*)(Ads2t + d * DS + q * 4);
    const float Dd = Dw[d];

    float h[16];
    size_t cbase = ((size_t)(b * DI + d) * NCHUNK + chunk) * DS;
#pragma unroll
    for (int q = 0; q < 4; ++q) {
        float4 c4 = *(const float4*)(carry + cbase + q * 4);
        h[q*4] = c4.x; h[q*4+1] = c4.y; h[q*4+2] = c4.z; h[q*4+3] = c4.w;
    }
    __syncthreads();

    const float* dtp = dt + ((size_t)b * LSEQ + l0) * DI + d;
    const float* xcp = xc + ((size_t)b * LSEQ + l0) * DI + d;
    const float* zp  = xz + ((size_t)b * LSEQ + l0) * NIN + DI + d;   // already silu'd
    unsigned short* yhp = yh + ((size_t)b * LSEQ + l0) * DI + d;
    unsigned short* ylp = yl + ((size_t)b * LSEQ + l0) * DI + d;

#pragma unroll 4
    for (int i = 0; i < LCHUNK; ++i) {
        float dtv = dtp[(size_t)i * DI];
        float xcv = xcp[(size_t)i * DI];
        float zs  = zp[(size_t)i * NIN];
        float du  = dtv * xcv;
        float4 b0 = *(float4*)(&BC[i][0]);
        float4 b1 = *(float4*)(&BC[i][4]);
        float4 b2 = *(float4*)(&BC[i][8]);
        float4 b3 = *(float4*)(&BC[i][12]);
        float4 c0 = *(float4*)(&BC[i][16]);
        float4 c1 = *(float4*)(&BC[i][20]);
        float4 c2 = *(float4*)(&BC[i][24]);
        float4 c3 = *(float4*)(&BC[i][28]);
        float bv[16] = {b0.x,b0.y,b0.z,b0.w, b1.x,b1.y,b1.z,b1.w,
                        b2.x,b2.y,b2.z,b2.w, b3.x,b3.y,b3.z,b3.w};
        float cv[16] = {c0.x,c0.y,c0.z,c0.w, c1.x,c1.y,c1.z,c1.w,
                        c2.x,c2.y,c2.z,c2.w, c3.x,c3.y,c3.z,c3.w};
        float yv = 0.f;
#pragma unroll
        for (int s = 0; s < 16; ++s) {
            float a = exp2_f(dtv * Ads2[s]);
            h[s] = fmaf(h[s], a, du * bv[s]);
            yv = fmaf(h[s], cv[s], yv);
        }
        float yf = fmaf(xcv, Dd, yv) * zs;
        unsigned int hh = bf16_rne(yf);
        float rr = yf - __uint_as_float(hh << 16);
        yhp[(size_t)i * DI] = (unsigned short)hh;
        ylp[(size_t)i * DI] = (unsigned short)bf16_rne(rr);
    }
}

// ---------------- gemm_out (MFMA bf16x3): out[b,c,l] = sum_d y[b,l,d] * W_out[d,c] ----------------
// A (y) arrives pre-split -> staging is pure copies.
__global__ __launch_bounds__(256) void gemm_out_k(const unsigned short* __restrict__ yh,
                                                  const unsigned short* __restrict__ yl,
                                                  const unsigned short* __restrict__ WT_hi,
                                                  const unsigned short* __restrict__ WT_lo,
                                                  float* __restrict__ out) {
    __shared__ unsigned short sA[128][40];
    __shared__ unsigned short sB[128][40];
    const int b  = blockIdx.z;
    const int m0 = blockIdx.y * 64;    // l
    const int n0 = blockIdx.x * 64;    // c
    const int t  = threadIdx.x;
    const int w    = t >> 6;
    const int lane = t & 63;
    const int mwb = (w & 1) * 32;
    const int nwb = (w >> 1) * 32;
    const int fr  = lane & 15;
    const int q   = lane >> 4;

    const int row = t >> 2;
    const int kq8 = (t & 3) * 8;

    floatx4 acc[2][2];
#pragma unroll
    for (int mi = 0; mi < 2; ++mi)
#pragma unroll
        for (int ni = 0; ni < 2; ++ni) acc[mi][ni] = (floatx4){0.f, 0.f, 0.f, 0.f};

    for (int k0 = 0; k0 < DI; k0 += 32) {
        {
            const size_t aoff = ((size_t)b * LSEQ + m0 + row) * DI + k0 + kq8;
            *(short8*)&sA[row][kq8]      = *(const short8*)(yh + aoff);
            *(short8*)&sA[64 + row][kq8] = *(const short8*)(yl + aoff);

            const size_t boff = (size_t)(n0 + row) * DM + k0 + kq8;
            *(short8*)&sB[row][kq8]      = *(const short8*)(WT_hi + boff);
            *(short8*)&sB[64 + row][kq8] = *(const short8*)(WT_lo + boff);
        }
        __syncthreads();

        short8 ah[2], al[2], bh[2], bl[2];
#pragma unroll
        for (int mi = 0; mi < 2; ++mi) {
            int mr = mwb + mi * 16 + fr;
            ah[mi] = *(const short8*)&sA[mr][q * 8];
            al[mi] = *(const short8*)&sA[64 + mr][q * 8];
        }
#pragma unroll
        for (int ni = 0; ni < 2; ++ni) {
            int nr = nwb + ni * 16 + fr;
            bh[ni] = *(const short8*)&sB[nr][q * 8];
            bl[ni] = *(const short8*)&sB[64 + nr][q * 8];
        }
#pragma unroll
        for (int mi = 0; mi < 2; ++mi)
#pragma unroll
            for (int ni = 0; ni < 2; ++ni) {
                acc[mi][ni] = __builtin_amdgcn_mfma_f32_16x16x32_bf16(ah[mi], bh[ni], acc[mi][ni], 0, 0, 0);
                acc[mi][ni] = __builtin_amdgcn_mfma_f32_16x16x32_bf16(ah[mi], bl[ni], acc[mi][ni], 0, 0, 0);
                acc[mi][ni] = __builtin_amdgcn_mfma_f32_16x16x32_bf16(al[mi], bh[ni], acc[mi][ni], 0, 0, 0);
            }
        __syncthreads();
    }

#pragma unroll
    for (int mi = 0; mi < 2; ++mi)
#pragma unroll
        for (int ni = 0; ni < 2; ++ni) {
            int c = n0 + nwb + ni * 16 + fr;
            float* op = out + ((size_t)b * DM + c) * LSEQ + m0 + mwb + mi * 16 + q * 4;
            *(float4*)op = make_float4(acc[mi][ni][0], acc[mi][ni][1],
                                       acc[mi][ni][2], acc[mi][ni][3]);
        }
}

extern "C" void kernel_launch(void* const* d_in, const int* in_sizes, int n_in,
                              void* d_out, int out_size, void* d_ws, size_t ws_size,
                              hipStream_t stream) {
    const float* x      = (const float*)d_in[0];
    const float* W_in   = (const float*)d_in[1];
    const float* conv_w = (const float*)d_in[2];
    const float* conv_b = (const float*)d_in[3];
    const float* W_x    = (const float*)d_in[4];
    const float* W_dt   = (const float*)d_in[5];
    const float* b_dt   = (const float*)d_in[6];
    const float* A_log  = (const float*)d_in[7];
    const float* Dw     = (const float*)d_in[8];
    const float* W_out  = (const float*)d_in[9];
    float* out = (float*)d_out;

    float* ws    = (float*)d_ws;
    float* xz    = ws;                    // B*L*512            = 4,194,304
    float* xc    = xz + 4194304;          // B*L*256            = 2,097,152
    float* bc    = xc + 2097152;          // B*L*32             =   262,144
    float* dtb   = bc + 262144;           // B*L*256            = 2,097,152
    float* sumdt = dtb + 2097152;         // B*DI*NCHUNK        =   131,072
    float* Fst   = sumdt + 131072;        // B*DI*NCHUNK*DS     = 2,097,152
    float* yreg  = Fst + 2097152;         // y hi/lo region (2,097,152 floats worth)
    unsigned short* yh = (unsigned short*)yreg;                   // B*L*DI ushorts
    unsigned short* yl = yh + 2097152;
    unsigned short* WinT_hi  = (unsigned short*)(yreg + 2097152); // 512*256
    unsigned short* WinT_lo  = WinT_hi + 131072;
    unsigned short* WoutT_hi = WinT_lo + 131072;                  // 256*256
    unsigned short* WoutT_lo = WoutT_hi + 65536;
    unsigned short* BcatT_hi = WoutT_lo + 65536;                  // 320*256
    unsigned short* BcatT_lo = BcatT_hi + 81920;
    float* Ads2t = (float*)(BcatT_lo + 81920);                    // 256*16

    setup_k    <<<dim3(256), 512, 0, stream>>>(W_in, W_out, W_x, W_dt, A_log,
                                               WinT_hi, WinT_lo, WoutT_hi, WoutT_lo,
                                               BcatT_hi, BcatT_lo, Ads2t);
    gemm_in_k  <<<dim3(8, 64, BSZ), 256, 0, stream>>>(x, WinT_hi, WinT_lo, xz);
    gemm_x2c_k <<<dim3(5, 128), 256, 0, stream>>>(xz, conv_w, conv_b,
                                                  BcatT_hi, BcatT_lo, b_dt, xc, dtb, bc);
    scan_a_k   <<<dim3(BSZ * NCHUNK), 256, 0, stream>>>(dtb, xc, bc, Ads2t, sumdt, Fst);
    scan_b_k   <<<dim3(BSZ * DI), 256, 0, stream>>>(sumdt, Ads2t, Fst);
    scan_c_k   <<<dim3(BSZ * NCHUNK), 256, 0, stream>>>(dtb, xc, bc, xz, Ads2t, Dw, Fst, yh, yl);
    gemm_out_k <<<dim3(4, 64, BSZ), 256, 0, stream>>>(yh, yl, WoutT_hi, WoutT_lo, out);
}